// Round 11
// baseline (110.274 us; speedup 1.0000x reference)
//
#include <hip/hip_runtime.h>
#include <hip/hip_bf16.h>
#include <cstdint>

#define B_SIZE 4096
#define TWO_B  8192
#define DIM    512           // row length; i8 => 512 bytes per row
#define NBLK   1056          // blocks: (I,J), I in [0,32), J in [2I,64)
// exp(sim/t) with sim = acc/127^2, t=0.5: exp2(acc * log2(e)/(t*16129))
#define IEXP_SCALE 1.7889578968877387e-4f

typedef __attribute__((ext_vector_type(4))) float f32x4;
typedef __attribute__((ext_vector_type(4))) int   i32x4;

// raw waitcnt: vmcnt(n) with lgkmcnt/expcnt unconstrained (gfx9 encoding)
#define WAITVM(n) __builtin_amdgcn_s_waitcnt(0xF70 | (n))
#define BARRIER() __builtin_amdgcn_s_barrier()

// ---------- helpers ----------
__device__ __forceinline__ void async16(const void* g, void* l) {
    __builtin_amdgcn_global_load_lds(
        (const __attribute__((address_space(1))) unsigned int*)g,
        (__attribute__((address_space(3))) unsigned int*)l,
        16, 0, 0);
}

// ---------- kernel 1: L2-normalize rows -> i8 reps (scale 127), fp32 positives ----------
__global__ __launch_bounds__(256) void norm_pos_kernel(
    const float* __restrict__ emb_i, const float* __restrict__ emb_j,
    unsigned char* __restrict__ reps, float* __restrict__ pos,
    float* __restrict__ out)
{
    __shared__ float sc[3][4];
    int b = blockIdx.x, t = threadIdx.x;
    if (b == 0 && t == 0) out[0] = 0.0f;       // loss kernel accumulates atomically

    const float2* ri = (const float2*)(emb_i + (size_t)b * DIM);
    const float2* rj = (const float2*)(emb_j + (size_t)b * DIM);
    float2 xi = ri[t], xj = rj[t];
    float si = xi.x * xi.x + xi.y * xi.y;
    float sj = xj.x * xj.x + xj.y * xj.y;
    #pragma unroll
    for (int o = 32; o > 0; o >>= 1) { si += __shfl_down(si, o, 64); sj += __shfl_down(sj, o, 64); }
    int lane = t & 63, w = t >> 6;
    if (lane == 0) { sc[0][w] = si; sc[1][w] = sj; }
    __syncthreads();
    float ni2 = sc[0][0] + sc[0][1] + sc[0][2] + sc[0][3];
    float nj2 = sc[1][0] + sc[1][1] + sc[1][2] + sc[1][3];
    float rni = 1.0f / fmaxf(sqrtf(ni2), 1e-12f);
    float rnj = 1.0f / fmaxf(sqrtf(nj2), 1e-12f);
    float zix = xi.x * rni, ziy = xi.y * rni;
    float zjx = xj.x * rnj, zjy = xj.y * rnj;
    // symmetric i8 quant, scale 127 (|z| <= 1 -> |q| <= 127, exact i32 dot later)
    int qix = __float2int_rn(zix * 127.0f), qiy = __float2int_rn(ziy * 127.0f);
    int qjx = __float2int_rn(zjx * 127.0f), qjy = __float2int_rn(zjy * 127.0f);
    ((unsigned short*)(reps + (size_t)b * DIM))[t] =
        (unsigned short)((qix & 0xFF) | ((qiy & 0xFF) << 8));
    ((unsigned short*)(reps + (size_t)(b + B_SIZE) * DIM))[t] =
        (unsigned short)((qjx & 0xFF) | ((qjy & 0xFF) << 8));
    float d = zix * zjx + ziy * zjy;
    #pragma unroll
    for (int o = 32; o > 0; o >>= 1) d += __shfl_down(d, o, 64);
    if (lane == 0) sc[2][w] = d;
    __syncthreads();
    if (t == 0) pos[b] = sc[2][0] + sc[2][1] + sc[2][2] + sc[2][3];
}

// ---------- kernel 2: symmetric fused R*R^T (i8 MFMA) + masked exp row/col sums ----------
// ROUND 11: 3-buffer rotation, ONE barrier per K-iter (was 2). stage at iter k writes
// buf (k+2)%3 == (k-1)%3, whose readers finished compute(k-1) BEFORE this iter's barrier
// (a wave at the barrier has issued its MFMAs, so its ds_reads completed). vmcnt counting
// unchanged: 3 DMAs/stage, WAITVM(3) drains tile k, keeps tile k+1 in flight.
// LDS = 72 KB; occupancy still 2 blocks/CU (regs cap 8-wave blocks at 2; 2x72<=160 KB).
// 8 barriers + 1 pre-epilogue + 1 pre-reduce (was 16 + 1) — removes the r10 residue's
// dominant term (barrier convergence/skew, ~1.6 us-equivalent each).
// i8 core (verified r10): mfma_i32_16x16x64_i8, 16 MFMA + 8 ds_read_b128 per wave/iter,
// conflict-free swizzled pieces. acc i32x4[4][4] = 64 AGPR, sim = acc/127^2.
// Skeleton (verified r6-r10): 256x128 tile, 8 waves of 64x64, launch_bounds(512,4);
// band-decoded (I,J) with J>=2I; atomic-free part[64][8192], each slot written once.
#define BK 64
#define KITERS 8             // DIM / BK
#define RSTR 20              // red row stride in words (80 B: 16-aligned, bank-spread)

__global__ __launch_bounds__(512, 4) void sim_denom_kernel(
    const unsigned char* __restrict__ reps,
    const int* __restrict__ target,
    float* __restrict__ part)
{
    // unified LDS: staging [A0 16K | A1 16K | A2 16K | B0 8K | B1 8K | B2 8K] = 72 KB;
    // epilogue overlay [red0 20K | red1 20K | red_col 2K] = 42 KB (fenced by post-loop barrier)
    __shared__ __align__(16) unsigned char SMEM[73728];
    unsigned char* Ab[3] = { SMEM, SMEM + 16384, SMEM + 32768 };
    unsigned char* Bb[3] = { SMEM + 49152, SMEM + 57344, SMEM + 65536 };

    int t = threadIdx.x;
    // XCD-chunked remap: contiguous 132-run per XCD (1056 = 8*132, bijective).
    int id0 = blockIdx.x;
    int id = (id0 & 7) * 132 + (id0 >> 3);

    // --- band decode: 8x16 (I,J) supertile bands over the J>=2I region ---
    const int bA[10]   = {0,0,0,0,1,1,1,2,2,3};
    const int bB[10]   = {0,1,2,3,1,2,3,2,3,3};
    const int boff[11] = {0,72,200,328,456,528,656,784,856,984,1056};
    int s = 0;
    while (boff[s + 1] <= id) s++;
    int l = id - boff[s];
    int I, J;
    if (bA[s] == bB[s]) {                 // triangular band: start(r) = r*(17-r)
        int r = 0;
        while ((r + 1) * (16 - r) <= l) r++;
        I = bA[s] * 8 + r;
        J = bB[s] * 16 + 2 * r + (l - r * (17 - r));
    } else { I = bA[s] * 8 + (l >> 4); J = bB[s] * 16 + (l & 15); }

    int brow = I * 256;
    int bcol = J * 128;

    int wave = t >> 6, lane = t & 63;
    int wr = wave >> 1, wc = wave & 1;       // 4x2 waves, each 64x64 output
    int quad = lane >> 4, lm = lane & 15;

    i32x4 acc[4][4];
    #pragma unroll
    for (int i = 0; i < 4; i++)
        #pragma unroll
        for (int j = 0; j < 4; j++) acc[i][j] = (i32x4)0;

    // staging: A: 2 calls, call c -> row c*128 + (t>>2), LDS byte t*16 + c*8192;
    // B: 1 call, row t>>2. swizzled source piece = (t&3) ^ ((row ^ (row>>2)) & 3)
    int srow = t >> 2;
    int sp   = (t & 3) ^ ((srow ^ (srow >> 2)) & 3);
    const unsigned char* gA = reps + (size_t)(brow + srow) * DIM + sp * 16;
    const unsigned char* gB = reps + (size_t)(bcol + srow) * DIM + sp * 16;

    auto stage = [&](unsigned char* Abuf, unsigned char* Bbuf, int k0) {
        async16(gA + k0, Abuf + t * 16);
        async16(gA + k0 + 128 * DIM, Abuf + t * 16 + 8192);
        async16(gB + k0, Bbuf + t * 16);
    };
    auto compute = [&](const unsigned char* Abuf, const unsigned char* Bbuf) {
        i32x4 bf[4];
        #pragma unroll
        for (int ni = 0; ni < 4; ni++) {
            int cl = wc * 64 + ni * 16 + lm;               // 0..127
            int p = quad ^ ((cl ^ (cl >> 2)) & 3);
            bf[ni] = *(const i32x4*)(Bbuf + cl * 64 + p * 16);
        }
        #pragma unroll
        for (int mi = 0; mi < 4; mi++) {
            int rl = wr * 64 + mi * 16 + lm;               // 0..255
            int p = quad ^ ((rl ^ (rl >> 2)) & 3);
            i32x4 af = *(const i32x4*)(Abuf + rl * 64 + p * 16);
            #pragma unroll
            for (int ni = 0; ni < 4; ni++)
                acc[mi][ni] = __builtin_amdgcn_mfma_i32_16x16x64_i8(
                    af, bf[ni], acc[mi][ni], 0, 0, 0);
        }
    };

    // prologue: two tiles in flight (6 DMAs outstanding per thread)
    stage(Ab[0], Bb[0], 0);
    stage(Ab[1], Bb[1], BK);

    #pragma unroll
    for (int k = 0; k < KITERS; k++) {
        if (k < KITERS - 1) WAITVM(3); else WAITVM(0);   // drain loads(k), keep loads(k+1)
        BARRIER();   // tile k valid everywhere; all waves done reading buf (k-1)%3 == (k+2)%3
        compute(Ab[k % 3], Bb[k % 3]);
        if (k + 2 < KITERS) stage(Ab[(k + 2) % 3], Bb[(k + 2) % 3], (k + 2) * BK);
    }
    BARRIER();       // all waves past compute(7) before the epilogue LDS overlay

    // ---------- epilogue: masked exp + row/col sums, atomic-free, shfl-free rows ----------
    // C/D layout: col=lane&15, row=quad*4+reg. Wave's rows all in one 128-half h.
    // Positives: global col-row = 4096 <=> (J - rtile)==32 at ((rl&127)==cl).
    int h = wr >> 1;
    int rtile = 2 * I + h;
    bool haspos = (J - rtile == 32);
    int labc[4];
    #pragma unroll
    for (int ni = 0; ni < 4; ni++)
        labc[ni] = target[(bcol + wc * 64 + ni * 16 + lm) & (B_SIZE - 1)];

    float* red0    = (float*)SMEM;               // [256][RSTR] lm-partials, wc=0
    float* red1    = (float*)(SMEM + 20480);     // [256][RSTR] lm-partials, wc=1
    float* red_col = (float*)(SMEM + 40960);     // [2][2][128] col partials
    float* redw    = wc ? red1 : red0;

    float colacc[4] = {0.f, 0.f, 0.f, 0.f};
    #pragma unroll
    for (int mi = 0; mi < 4; mi++) {
        #pragma unroll
        for (int r = 0; r < 4; r++) {
            int rl = wr * 64 + mi * 16 + quad * 4 + r;     // 0..255
            int labr = target[(brow + rl) & (B_SIZE - 1)];
            float rowacc = 0.0f;
            #pragma unroll
            for (int ni = 0; ni < 4; ni++) {
                int cl = wc * 64 + ni * 16 + lm;
                bool pospair = haspos && ((rl & 127) == cl);
                bool masked = (labr == labc[ni]) && !pospair;
                float e = masked ? 0.0f
                                 : __builtin_amdgcn_exp2f(
                                       (float)acc[mi][ni][r] * IEXP_SCALE);
                rowacc += e;
                colacc[ni] += e;
            }
            redw[rl * RSTR + lm] = rowacc;       // all 64 lanes, distinct (rl,lm) slots
        }
    }
    #pragma unroll
    for (int ni = 0; ni < 4; ni++) {
        float c = colacc[ni];
        c += __shfl_xor(c, 16, 64);
        c += __shfl_xor(c, 32, 64);
        if (quad == 0) red_col[h * 256 + (wr & 1) * 128 + wc * 64 + ni * 16 + lm] = c;
    }
    BARRIER();
    if (t < 256) {
        int th = t >> 7;                       // row-half of this output row
        if (2 * I + th <= J) {                 // suppress even-diag duplicate lower half
            const f32x4* r0 = (const f32x4*)(red0 + t * RSTR);
            const f32x4* r1 = (const f32x4*)(red1 + t * RSTR);
            f32x4 v = r0[0] + r0[1] + r0[2] + r0[3]
                    + r1[0] + r1[1] + r1[2] + r1[3];
            part[(size_t)J * TWO_B + brow + t] = v[0] + v[1] + v[2] + v[3];
        }
    } else if (t < 512) {
        int c = t - 256;
        int ch = c >> 7, cc = c & 127;         // which row-half's col-sums
        int rt = 2 * I + ch;
        if (rt < J) {                          // skip diag (row-side covers) + duplicate half
            float cs = red_col[ch * 256 + cc] + red_col[ch * 256 + 128 + cc];
            part[(size_t)rt * TWO_B + bcol + cc] = cs;
        }
    }
}

// ---------- kernel 3: final loss (sum 64 part slices, then log/pos reduce) ----------
__global__ __launch_bounds__(256) void loss_kernel(
    const float* __restrict__ part, const float* __restrict__ pos,
    float* __restrict__ out)
{
    __shared__ float sc[4];
    int t = threadIdx.x, b = blockIdx.x;
    int i = b * 256 + t;
    float s = 0.0f;
    #pragma unroll
    for (int x = 0; x < 64; x++) s += part[(size_t)x * TWO_B + i];
    float v = logf(s + 1e-7f);                         // 32 blocks x 256 = 8192
    float p = (i < B_SIZE) ? pos[i] : 0.0f;
    // loss = (sum log(denom) - (2/t) * sum pos) / 2B ; 2/t = 4
    float v2 = v - 4.0f * p;
    #pragma unroll
    for (int o = 32; o > 0; o >>= 1) v2 += __shfl_down(v2, o, 64);
    int lane = t & 63, w = t >> 6;
    if (lane == 0) sc[w] = v2;
    __syncthreads();
    if (t == 0) atomicAdd(out, (sc[0] + sc[1] + sc[2] + sc[3]) * (1.0f / (float)TWO_B));
}

// ---------- launcher ----------
extern "C" void kernel_launch(void* const* d_in, const int* in_sizes, int n_in,
                              void* d_out, int out_size, void* d_ws, size_t ws_size,
                              hipStream_t stream)
{
    const float* emb_i  = (const float*)d_in[0];
    const float* emb_j  = (const float*)d_in[1];
    const int*   target = (const int*)d_in[2];
    float* out = (float*)d_out;

    char* ws = (char*)d_ws;
    unsigned char* reps = (unsigned char*)ws;                        // 8192*512 = 4 MB (i8)
    float* pos   = (float*)(ws + (size_t)TWO_B * DIM);               // 16 KB
    float* part  = (float*)(ws + (size_t)TWO_B * DIM + B_SIZE * 4);  // 64*8192*4 = 2 MB

    norm_pos_kernel<<<B_SIZE, 256, 0, stream>>>(emb_i, emb_j, reps, pos, out);
    sim_denom_kernel<<<NBLK, 512, 0, stream>>>(reps, target, part);
    loss_kernel<<<TWO_B / 256, 256, 0, stream>>>(part, pos, out);
}

// Round 12
// 108.580 us; speedup vs baseline: 1.0156x; 1.0156x over previous
//
#include <hip/hip_runtime.h>
#include <hip/hip_bf16.h>
#include <cstdint>

#define B_SIZE 4096
#define TWO_B  8192
#define DIM    512           // row length; i8 => 512 bytes per row
#define NBLK   1056          // blocks: (I,J), I in [0,32), J in [2I,64)
// exp(sim/t) with sim = acc/127^2, t=0.5: exp2(acc * log2(e)/(t*16129))
#define IEXP_SCALE 1.7889578968877387e-4f

typedef __attribute__((ext_vector_type(4))) float f32x4;
typedef __attribute__((ext_vector_type(4))) int   i32x4;

// raw waitcnt: vmcnt(n) with lgkmcnt/expcnt unconstrained (gfx9 encoding)
#define WAITVM(n) __builtin_amdgcn_s_waitcnt(0xF70 | (n))
#define BARRIER() __builtin_amdgcn_s_barrier()

// ---------- helpers ----------
__device__ __forceinline__ void async16(const void* g, void* l) {
    __builtin_amdgcn_global_load_lds(
        (const __attribute__((address_space(1))) unsigned int*)g,
        (__attribute__((address_space(3))) unsigned int*)l,
        16, 0, 0);
}

// ---------- kernel 1: L2-normalize rows -> i8 reps (scale 127), fp32 positives ----------
__global__ __launch_bounds__(256) void norm_pos_kernel(
    const float* __restrict__ emb_i, const float* __restrict__ emb_j,
    unsigned char* __restrict__ reps, float* __restrict__ pos,
    float* __restrict__ out)
{
    __shared__ float sc[3][4];
    int b = blockIdx.x, t = threadIdx.x;
    if (b == 0 && t == 0) out[0] = 0.0f;       // loss kernel accumulates atomically

    const float2* ri = (const float2*)(emb_i + (size_t)b * DIM);
    const float2* rj = (const float2*)(emb_j + (size_t)b * DIM);
    float2 xi = ri[t], xj = rj[t];
    float si = xi.x * xi.x + xi.y * xi.y;
    float sj = xj.x * xj.x + xj.y * xj.y;
    #pragma unroll
    for (int o = 32; o > 0; o >>= 1) { si += __shfl_down(si, o, 64); sj += __shfl_down(sj, o, 64); }
    int lane = t & 63, w = t >> 6;
    if (lane == 0) { sc[0][w] = si; sc[1][w] = sj; }
    __syncthreads();
    float ni2 = sc[0][0] + sc[0][1] + sc[0][2] + sc[0][3];
    float nj2 = sc[1][0] + sc[1][1] + sc[1][2] + sc[1][3];
    float rni = 1.0f / fmaxf(sqrtf(ni2), 1e-12f);
    float rnj = 1.0f / fmaxf(sqrtf(nj2), 1e-12f);
    float zix = xi.x * rni, ziy = xi.y * rni;
    float zjx = xj.x * rnj, zjy = xj.y * rnj;
    // symmetric i8 quant, scale 127 (|z| <= 1 -> |q| <= 127, exact i32 dot later)
    int qix = __float2int_rn(zix * 127.0f), qiy = __float2int_rn(ziy * 127.0f);
    int qjx = __float2int_rn(zjx * 127.0f), qjy = __float2int_rn(zjy * 127.0f);
    ((unsigned short*)(reps + (size_t)b * DIM))[t] =
        (unsigned short)((qix & 0xFF) | ((qiy & 0xFF) << 8));
    ((unsigned short*)(reps + (size_t)(b + B_SIZE) * DIM))[t] =
        (unsigned short)((qjx & 0xFF) | ((qjy & 0xFF) << 8));
    float d = zix * zjx + ziy * zjy;
    #pragma unroll
    for (int o = 32; o > 0; o >>= 1) d += __shfl_down(d, o, 64);
    if (lane == 0) sc[2][w] = d;
    __syncthreads();
    if (t == 0) pos[b] = sc[2][0] + sc[2][1] + sc[2][2] + sc[2][3];
}

// ---------- kernel 2: symmetric fused R*R^T (i8 MFMA, 2x fp8 rate) + masked exp sums ----------
// VERIFIED BEST (round 10, 106.5 us total): mfma_i32_16x16x64_i8 (K=64/instruction).
// Per wave per K-tile: 16 MFMAs + 8 ds_read_b128 (one swizzled 16-B piece per fragment:
// lane (lm,quad) needs k = quad*16..quad*16+15 = piece quad ^ swz -> 64 lanes cover 64
// distinct chunks, conflict-free). acc = i32x4[4][4] = 64 AGPR (exact integer dot,
// sim = acc/127^2). C/D layout shape-determined: col=lane&15, row=quad*4+reg.
// Skeleton: 256x128 tile, 8 waves of 64x64, launch_bounds(512,4) -> 2 blocks/CU;
// 2-buffer/2-barrier, counted vmcnt(3); epilogue = LDS-transpose reduction (r9);
// atomic-free part[64][8192]: slot part[x][tile g]: g<=x row-side of (g>>1,x);
// g>x col-side of (x>>1,g). Each written exactly once.
#define BK 64
#define KITERS 8             // DIM / BK
#define RSTR 20              // red row stride in words (80 B: 16-aligned, bank-spread)

__global__ __launch_bounds__(512, 4) void sim_denom_kernel(
    const unsigned char* __restrict__ reps,
    const int* __restrict__ target,
    float* __restrict__ part)
{
    // unified LDS: staging layout [As0 16K | As1 16K | Bs0 8K | Bs1 8K] = 48 KB;
    // epilogue overlay [red0 20K | red1 20K | red_col 2K] (fenced by k=7 barrier)
    __shared__ __align__(16) unsigned char SMEM[49152];
    unsigned char* As0 = SMEM;
    unsigned char* As1 = SMEM + 16384;
    unsigned char* Bs0 = SMEM + 32768;
    unsigned char* Bs1 = SMEM + 40960;

    int t = threadIdx.x;
    // XCD-chunked remap: contiguous 132-run per XCD (1056 = 8*132, bijective).
    int id0 = blockIdx.x;
    int id = (id0 & 7) * 132 + (id0 >> 3);

    // --- band decode: 8x16 (I,J) supertile bands over the J>=2I region ---
    const int bA[10]   = {0,0,0,0,1,1,1,2,2,3};
    const int bB[10]   = {0,1,2,3,1,2,3,2,3,3};
    const int boff[11] = {0,72,200,328,456,528,656,784,856,984,1056};
    int s = 0;
    while (boff[s + 1] <= id) s++;
    int l = id - boff[s];
    int I, J;
    if (bA[s] == bB[s]) {                 // triangular band: start(r) = r*(17-r)
        int r = 0;
        while ((r + 1) * (16 - r) <= l) r++;
        I = bA[s] * 8 + r;
        J = bB[s] * 16 + 2 * r + (l - r * (17 - r));
    } else { I = bA[s] * 8 + (l >> 4); J = bB[s] * 16 + (l & 15); }

    int brow = I * 256;
    int bcol = J * 128;

    int wave = t >> 6, lane = t & 63;
    int wr = wave >> 1, wc = wave & 1;       // 4x2 waves, each 64x64 output
    int quad = lane >> 4, lm = lane & 15;

    i32x4 acc[4][4];
    #pragma unroll
    for (int i = 0; i < 4; i++)
        #pragma unroll
        for (int j = 0; j < 4; j++) acc[i][j] = (i32x4)0;

    // staging: A: 2 calls, call c -> row c*128 + (t>>2), LDS byte t*16 + c*8192;
    // B: 1 call, row t>>2. swizzled source piece = (t&3) ^ ((row ^ (row>>2)) & 3)
    int srow = t >> 2;
    int sp   = (t & 3) ^ ((srow ^ (srow >> 2)) & 3);
    const unsigned char* gA = reps + (size_t)(brow + srow) * DIM + sp * 16;
    const unsigned char* gB = reps + (size_t)(bcol + srow) * DIM + sp * 16;

    auto stage = [&](unsigned char* Ab, unsigned char* Bb, int k0) {
        async16(gA + k0, Ab + t * 16);
        async16(gA + k0 + 128 * DIM, Ab + t * 16 + 8192);
        async16(gB + k0, Bb + t * 16);
    };
    auto compute = [&](const unsigned char* Ab, const unsigned char* Bb) {
        i32x4 bf[4];
        #pragma unroll
        for (int ni = 0; ni < 4; ni++) {
            int cl = wc * 64 + ni * 16 + lm;               // 0..127
            int p = quad ^ ((cl ^ (cl >> 2)) & 3);
            bf[ni] = *(const i32x4*)(Bb + cl * 64 + p * 16);
        }
        #pragma unroll
        for (int mi = 0; mi < 4; mi++) {
            int rl = wr * 64 + mi * 16 + lm;               // 0..255
            int p = quad ^ ((rl ^ (rl >> 2)) & 3);
            i32x4 af = *(const i32x4*)(Ab + rl * 64 + p * 16);
            #pragma unroll
            for (int ni = 0; ni < 4; ni++)
                acc[mi][ni] = __builtin_amdgcn_mfma_i32_16x16x64_i8(
                    af, bf[ni], acc[mi][ni], 0, 0, 0);
        }
    };

    // prologue: two tiles in flight (6 DMAs outstanding per thread)
    stage(As0, Bs0, 0);
    stage(As1, Bs1, BK);

    #pragma unroll
    for (int k = 0; k < KITERS; k++) {
        unsigned char* Ac = (k & 1) ? As1 : As0;
        unsigned char* Bc = (k & 1) ? Bs1 : Bs0;
        if (k < KITERS - 1) WAITVM(3); else WAITVM(0);   // drain loads(k), keep loads(k+1) in flight
        BARRIER();                         // all waves' loads(k) landed
        compute(Ac, Bc);
        BARRIER();                         // all waves done reading buf(k)
        if (k + 2 < KITERS) stage(Ac, Bc, (k + 2) * BK);
    }

    // ---------- epilogue: masked exp + row/col sums, atomic-free, shfl-free rows ----------
    // C/D layout: col=lane&15, row=quad*4+reg. Wave's rows all in one 128-half h.
    // Positives: global col-row = 4096 <=> (J - rtile)==32 at ((rl&127)==cl).
    int h = wr >> 1;
    int rtile = 2 * I + h;
    bool haspos = (J - rtile == 32);
    int labc[4];
    #pragma unroll
    for (int ni = 0; ni < 4; ni++)
        labc[ni] = target[(bcol + wc * 64 + ni * 16 + lm) & (B_SIZE - 1)];

    float* red0    = (float*)SMEM;               // [256][RSTR] lm-partials, wc=0
    float* red1    = (float*)(SMEM + 20480);     // [256][RSTR] lm-partials, wc=1
    float* red_col = (float*)(SMEM + 40960);     // [2][2][128] col partials
    float* redw    = wc ? red1 : red0;

    float colacc[4] = {0.f, 0.f, 0.f, 0.f};
    #pragma unroll
    for (int mi = 0; mi < 4; mi++) {
        #pragma unroll
        for (int r = 0; r < 4; r++) {
            int rl = wr * 64 + mi * 16 + quad * 4 + r;     // 0..255
            int labr = target[(brow + rl) & (B_SIZE - 1)];
            float rowacc = 0.0f;
            #pragma unroll
            for (int ni = 0; ni < 4; ni++) {
                int cl = wc * 64 + ni * 16 + lm;
                bool pospair = haspos && ((rl & 127) == cl);
                bool masked = (labr == labc[ni]) && !pospair;
                float e = masked ? 0.0f
                                 : __builtin_amdgcn_exp2f(
                                       (float)acc[mi][ni][r] * IEXP_SCALE);
                rowacc += e;
                colacc[ni] += e;
            }
            redw[rl * RSTR + lm] = rowacc;       // all 64 lanes, distinct (rl,lm) slots
        }
    }
    #pragma unroll
    for (int ni = 0; ni < 4; ni++) {
        float c = colacc[ni];
        c += __shfl_xor(c, 16, 64);
        c += __shfl_xor(c, 32, 64);
        if (quad == 0) red_col[h * 256 + (wr & 1) * 128 + wc * 64 + ni * 16 + lm] = c;
    }
    BARRIER();
    if (t < 256) {
        int th = t >> 7;                       // row-half of this output row
        if (2 * I + th <= J) {                 // suppress even-diag duplicate lower half
            const f32x4* r0 = (const f32x4*)(red0 + t * RSTR);
            const f32x4* r1 = (const f32x4*)(red1 + t * RSTR);
            f32x4 v = r0[0] + r0[1] + r0[2] + r0[3]
                    + r1[0] + r1[1] + r1[2] + r1[3];
            part[(size_t)J * TWO_B + brow + t] = v[0] + v[1] + v[2] + v[3];
        }
    } else if (t < 512) {
        int c = t - 256;
        int ch = c >> 7, cc = c & 127;         // which row-half's col-sums
        int rt = 2 * I + ch;
        if (rt < J) {                          // skip diag (row-side covers) + duplicate half
            float cs = red_col[ch * 256 + cc] + red_col[ch * 256 + 128 + cc];
            part[(size_t)rt * TWO_B + bcol + cc] = cs;
        }
    }
}

// ---------- kernel 3: final loss (sum 64 part slices, then log/pos reduce) ----------
__global__ __launch_bounds__(256) void loss_kernel(
    const float* __restrict__ part, const float* __restrict__ pos,
    float* __restrict__ out)
{
    __shared__ float sc[4];
    int t = threadIdx.x, b = blockIdx.x;
    int i = b * 256 + t;
    float s = 0.0f;
    #pragma unroll
    for (int x = 0; x < 64; x++) s += part[(size_t)x * TWO_B + i];
    float v = logf(s + 1e-7f);                         // 32 blocks x 256 = 8192
    float p = (i < B_SIZE) ? pos[i] : 0.0f;
    // loss = (sum log(denom) - (2/t) * sum pos) / 2B ; 2/t = 4
    float v2 = v - 4.0f * p;
    #pragma unroll
    for (int o = 32; o > 0; o >>= 1) v2 += __shfl_down(v2, o, 64);
    int lane = t & 63, w = t >> 6;
    if (lane == 0) sc[w] = v2;
    __syncthreads();
    if (t == 0) atomicAdd(out, (sc[0] + sc[1] + sc[2] + sc[3]) * (1.0f / (float)TWO_B));
}

// ---------- launcher ----------
extern "C" void kernel_launch(void* const* d_in, const int* in_sizes, int n_in,
                              void* d_out, int out_size, void* d_ws, size_t ws_size,
                              hipStream_t stream)
{
    const float* emb_i  = (const float*)d_in[0];
    const float* emb_j  = (const float*)d_in[1];
    const int*   target = (const int*)d_in[2];
    float* out = (float*)d_out;

    char* ws = (char*)d_ws;
    unsigned char* reps = (unsigned char*)ws;                        // 8192*512 = 4 MB (i8)
    float* pos   = (float*)(ws + (size_t)TWO_B * DIM);               // 16 KB
    float* part  = (float*)(ws + (size_t)TWO_B * DIM + B_SIZE * 4);  // 64*8192*4 = 2 MB

    norm_pos_kernel<<<B_SIZE, 256, 0, stream>>>(emb_i, emb_j, reps, pos, out);
    sim_denom_kernel<<<NBLK, 512, 0, stream>>>(reps, target, part);
    loss_kernel<<<TWO_B / 256, 256, 0, stream>>>(part, pos, out);
}